// Round 6
// baseline (144.478 us; speedup 1.0000x reference)
//
#include <hip/hip_runtime.h>
#include <math.h>

#define C 64
#define IN_DIM 148
#define ODIM 9      // outputs per edge
#define PROW 10     // halfs per proj row (20 B packed; sp+dp = 4.0 MB, L2-resident)
#define EPT 4       // edges per thread in edge kernel

typedef _Float16 half_t;
typedef float f4 __attribute__((ext_vector_type(4)));
typedef f4 f4u __attribute__((aligned(4)));
typedef int i4 __attribute__((ext_vector_type(4)));
typedef _Float16 h8 __attribute__((ext_vector_type(8)));
typedef h8 h8u __attribute__((aligned(4)));
typedef _Float16 h2 __attribute__((ext_vector_type(2)));

__device__ __forceinline__ float tanh_fast(float x) {
    // tanh(x) = 1 - 2/(e^{2x}+1); saturates correctly at +/-inf
    float e = __expf(2.0f * x);
    return 1.0f - 2.0f / (e + 1.0f);
}

// ---------------- node projection kernel: 1 thread per node, fdot2 ----------
__global__ __launch_bounds__(256) void node_proj_kernel(
    const float* __restrict__ x, const int* __restrict__ node_types,
    const float* __restrict__ W, half_t* __restrict__ sp, half_t* __restrict__ dp,
    int N)
{
    __shared__ _Float16 Wh[2 * ODIM][C];   // r<9: W[r][c]; r>=9: W[r-9][64+c]  (fp16)
    __shared__ float ntab[2][ODIM][4];     // [0]=src-type consts, [1]=dst-type consts

    for (int i = threadIdx.x; i < 2 * ODIM * C; i += 256) {
        int r = i >> 6, c = i & 63;
        int o = (r < ODIM) ? r : r - ODIM;
        int col = (r < ODIM) ? c : (C + c);
        Wh[r][c] = (_Float16)W[o * IN_DIM + col];
    }
    for (int i = threadIdx.x; i < 2 * ODIM * 4; i += 256) {
        int t = i & 3;
        int o = (i >> 2) % ODIM;
        int sd = (i >> 2) / ODIM;
        ntab[sd][o][t] = W[o * IN_DIM + 128 + sd * 4 + t];
    }
    __syncthreads();

    int n = blockIdx.x * 256 + threadIdx.x;
    if (n >= N) return;

    // x row -> fp16 pairs in registers (32 VGPR)
    const f4* xr = (const f4*)(x + (size_t)n * C);
    h2 xh[32];
#pragma unroll
    for (int q = 0; q < 16; ++q) {
        f4 v = xr[q];
        xh[2 * q]     = h2{(_Float16)v.x, (_Float16)v.y};
        xh[2 * q + 1] = h2{(_Float16)v.z, (_Float16)v.w};
    }

    float acc[2 * ODIM];
#pragma unroll
    for (int o = 0; o < 2 * ODIM; ++o) acc[o] = 0.0f;

#pragma unroll
    for (int g = 0; g < 8; ++g) {          // 8 halfs (16B) per group
#pragma unroll
        for (int o = 0; o < 2 * ODIM; ++o) {
            h8 wv = *(const h8*)&Wh[o][g * 8];   // one ds_read_b128, broadcast
            const h2* wp = (const h2*)&wv;
            acc[o] = __builtin_amdgcn_fdot2(xh[4 * g + 0], wp[0], acc[o], false);
            acc[o] = __builtin_amdgcn_fdot2(xh[4 * g + 1], wp[1], acc[o], false);
            acc[o] = __builtin_amdgcn_fdot2(xh[4 * g + 2], wp[2], acc[o], false);
            acc[o] = __builtin_amdgcn_fdot2(xh[4 * g + 3], wp[3], acc[o], false);
        }
    }

    int t = node_types[n];
    half_t srow[PROW], drow[PROW];
#pragma unroll
    for (int o = 0; o < ODIM; ++o) {
        srow[o] = (half_t)(acc[o] + ntab[0][o][t]);
        drow[o] = (half_t)(acc[ODIM + o] + ntab[1][o][t]);
    }
    srow[9] = (half_t)0.0f;
    drow[9] = (half_t)0.0f;

    half_t* srp = sp + (size_t)n * PROW;
    half_t* drp = dp + (size_t)n * PROW;
    *(h8u*)srp = *(h8*)srow;
    *(h2*)(srp + 8) = *(h2*)(srow + 8);
    *(h8u*)drp = *(h8*)drow;
    *(h2*)(drp + 8) = *(h2*)(drow + 8);
}

// ---------------- edge kernel: FOUR edges per thread ----------------
__global__ __launch_bounds__(256) void edge_kernel(
    const int* __restrict__ ei, const int* __restrict__ etypes,
    const half_t* __restrict__ sp, const half_t* __restrict__ dp,
    const float* __restrict__ W, float* __restrict__ out,
    int E)
{
    __shared__ float etab[12][ODIM];    // etab[t][o] = W[o][136+t]
    for (int i = threadIdx.x; i < 12 * ODIM; i += 256) {
        int t = i / ODIM, o = i - t * ODIM;
        etab[t][o] = W[o * IN_DIM + 136 + t];
    }
    __syncthreads();

    int tid = blockIdx.x * 256 + threadIdx.x;
    int e0 = tid * EPT;
    if (e0 >= E) return;

    i4 s4, d4, t4;
    if (e0 + EPT <= E) {
        // streaming, non-temporal: don't evict the L2-resident proj set
        s4 = __builtin_nontemporal_load((const i4*)(ei + e0));
        d4 = __builtin_nontemporal_load((const i4*)(ei + (size_t)E + e0));
        t4 = __builtin_nontemporal_load((const i4*)(etypes + e0));
    } else {
#pragma unroll
        for (int k = 0; k < EPT; ++k) {
            int e = e0 + k; if (e > E - 1) e = E - 1;
            s4[k] = ei[e]; d4[k] = ei[(size_t)E + e]; t4[k] = etypes[e];
        }
    }

    // 8 independent row gathers, all in flight
    h8 sv[EPT], dv[EPT];
    h2 sv2[EPT], dv2[EPT];
#pragma unroll
    for (int k = 0; k < EPT; ++k) {
        const half_t* srp = sp + (size_t)s4[k] * PROW;
        sv[k]  = *(const h8u*)srp;
        sv2[k] = *(const h2*)(srp + 8);
    }
#pragma unroll
    for (int k = 0; k < EPT; ++k) {
        const half_t* drp = dp + (size_t)d4[k] * PROW;
        dv[k]  = *(const h8u*)drp;
        dv2[k] = *(const h2*)(drp + 8);
    }

    if (e0 + EPT <= E) {
        float rr[EPT * ODIM];           // 144B contiguous, 16B-aligned at e0*36B
#pragma unroll
        for (int k = 0; k < EPT; ++k) {
            const float* eb = &etab[t4[k]][0];
#pragma unroll
            for (int o = 0; o < 8; ++o)
                rr[k * ODIM + o] = tanh_fast((float)sv[k][o] + (float)dv[k][o] + eb[o]);
            rr[k * ODIM + 8] = tanh_fast((float)sv2[k][0] + (float)dv2[k][0] + eb[8]);
        }
        float* op = out + (size_t)e0 * ODIM;
#pragma unroll
        for (int q = 0; q < EPT * ODIM / 4; ++q) {
            f4 v = {rr[4 * q], rr[4 * q + 1], rr[4 * q + 2], rr[4 * q + 3]};
            __builtin_nontemporal_store(v, (f4*)(op + 4 * q));   // 16B-aligned
        }
    } else {
#pragma unroll
        for (int k = 0; k < EPT; ++k) {
            if (e0 + k < E) {
                const float* eb = &etab[t4[k]][0];
                float* op = out + (size_t)(e0 + k) * ODIM;
#pragma unroll
                for (int o = 0; o < 8; ++o)
                    op[o] = tanh_fast((float)sv[k][o] + (float)dv[k][o] + eb[o]);
                op[8] = tanh_fast((float)sv2[k][0] + (float)dv2[k][0] + eb[8]);
            }
        }
    }
}

extern "C" void kernel_launch(void* const* d_in, const int* in_sizes, int n_in,
                              void* d_out, int out_size, void* d_ws, size_t ws_size,
                              hipStream_t stream) {
    const float* x      = (const float*)d_in[0];
    const int*   ei     = (const int*)d_in[1];
    const int*   etypes = (const int*)d_in[2];
    const int*   ntypes = (const int*)d_in[3];
    const float* W      = (const float*)d_in[4];
    float* out = (float*)d_out;

    int N = in_sizes[0] / C;    // 100000
    int E = in_sizes[2];        // 1600000

    half_t* sp = (half_t*)d_ws;
    half_t* dp = sp + (size_t)N * PROW;

    int nblocks = (N + 255) / 256;
    node_proj_kernel<<<nblocks, 256, 0, stream>>>(x, ntypes, W, sp, dp, N);

    int ethreads = (E + EPT - 1) / EPT;
    int eblocks  = (ethreads + 255) / 256;
    edge_kernel<<<eblocks, 256, 0, stream>>>(ei, etypes, sp, dp, W, out, E);
}

// Round 7
// 56.916 us; speedup vs baseline: 2.5384x; 2.5384x over previous
//
#include <hip/hip_runtime.h>
#include <math.h>

#define C 64
#define IN_DIM 148
#define ODIM 9      // outputs per edge
#define PROW 10     // halfs per proj row (20 B packed; sp+dp = 4.0 MB, L2-resident)

typedef _Float16 half_t;
typedef float f4 __attribute__((ext_vector_type(4)));
typedef f4 f4u __attribute__((aligned(4)));
typedef _Float16 h8 __attribute__((ext_vector_type(8)));
typedef h8 h8u __attribute__((aligned(4)));
typedef _Float16 h2 __attribute__((ext_vector_type(2)));

__device__ __forceinline__ float tanh_fast(float x) {
    // tanh(x) = 1 - 2/(e^{2x}+1); saturates correctly at +/-inf
    float e = __expf(2.0f * x);
    return 1.0f - 2.0f / (e + 1.0f);
}

// ---------------- node projection kernel: 1 thread per node, fdot2 ----------
__global__ __launch_bounds__(256) void node_proj_kernel(
    const float* __restrict__ x, const int* __restrict__ node_types,
    const float* __restrict__ W, half_t* __restrict__ sp, half_t* __restrict__ dp,
    int N)
{
    __shared__ _Float16 Wh[2 * ODIM][C];   // r<9: W[r][c]; r>=9: W[r-9][64+c]  (fp16)
    __shared__ float ntab[2][ODIM][4];     // [0]=src-type consts, [1]=dst-type consts

    for (int i = threadIdx.x; i < 2 * ODIM * C; i += 256) {
        int r = i >> 6, c = i & 63;
        int o = (r < ODIM) ? r : r - ODIM;
        int col = (r < ODIM) ? c : (C + c);
        Wh[r][c] = (_Float16)W[o * IN_DIM + col];
    }
    for (int i = threadIdx.x; i < 2 * ODIM * 4; i += 256) {
        int t = i & 3;
        int o = (i >> 2) % ODIM;
        int sd = (i >> 2) / ODIM;
        ntab[sd][o][t] = W[o * IN_DIM + 128 + sd * 4 + t];
    }
    __syncthreads();

    int n = blockIdx.x * 256 + threadIdx.x;
    if (n >= N) return;

    // x row -> fp16 pairs in registers
    const f4* xr = (const f4*)(x + (size_t)n * C);
    h2 xh[32];
#pragma unroll
    for (int q = 0; q < 16; ++q) {
        f4 v = xr[q];
        xh[2 * q]     = h2{(_Float16)v.x, (_Float16)v.y};
        xh[2 * q + 1] = h2{(_Float16)v.z, (_Float16)v.w};
    }

    float acc[2 * ODIM];
#pragma unroll
    for (int o = 0; o < 2 * ODIM; ++o) acc[o] = 0.0f;

#pragma unroll
    for (int g = 0; g < 8; ++g) {          // 8 halfs (16B) per group
#pragma unroll
        for (int o = 0; o < 2 * ODIM; ++o) {
            h8 wv = *(const h8*)&Wh[o][g * 8];   // one ds_read_b128, broadcast
            const h2* wp = (const h2*)&wv;
            acc[o] = __builtin_amdgcn_fdot2(xh[4 * g + 0], wp[0], acc[o], false);
            acc[o] = __builtin_amdgcn_fdot2(xh[4 * g + 1], wp[1], acc[o], false);
            acc[o] = __builtin_amdgcn_fdot2(xh[4 * g + 2], wp[2], acc[o], false);
            acc[o] = __builtin_amdgcn_fdot2(xh[4 * g + 3], wp[3], acc[o], false);
        }
    }

    int t = node_types[n];
    half_t srow[PROW], drow[PROW];
#pragma unroll
    for (int o = 0; o < ODIM; ++o) {
        srow[o] = (half_t)(acc[o] + ntab[0][o][t]);
        drow[o] = (half_t)(acc[ODIM + o] + ntab[1][o][t]);
    }
    srow[9] = (half_t)0.0f;
    drow[9] = (half_t)0.0f;

    half_t* srp = sp + (size_t)n * PROW;
    half_t* drp = dp + (size_t)n * PROW;
    *(h8u*)srp = *(h8*)srow;
    *(h2*)(srp + 8) = *(h2*)(srow + 8);
    *(h8u*)drp = *(h8*)drow;
    *(h2*)(drp + 8) = *(h2*)(drow + 8);
}

// ---------------- edge kernel: one thread per edge, PLAIN stores ------------
__global__ __launch_bounds__(256) void edge_kernel(
    const int* __restrict__ ei, const int* __restrict__ etypes,
    const half_t* __restrict__ sp, const half_t* __restrict__ dp,
    const float* __restrict__ W, float* __restrict__ out,
    int E)
{
    __shared__ float etab[12][ODIM];    // etab[t][o] = W[o][136+t]
    for (int i = threadIdx.x; i < 12 * ODIM; i += 256) {
        int t = i / ODIM, o = i - t * ODIM;
        etab[t][o] = W[o * IN_DIM + 136 + t];
    }
    __syncthreads();

    int e = blockIdx.x * 256 + threadIdx.x;
    if (e >= E) return;

    // streaming index loads: non-temporal so they don't evict the proj set
    int s  = __builtin_nontemporal_load(ei + e);
    int d  = __builtin_nontemporal_load(ei + (size_t)E + e);
    int et = __builtin_nontemporal_load(etypes + e);

    const half_t* srp = sp + (size_t)s * PROW;
    const half_t* drp = dp + (size_t)d * PROW;
    h8 sv  = *(const h8u*)srp;
    h2 sv2 = *(const h2*)(srp + 8);
    h8 dv  = *(const h8u*)drp;
    h2 dv2 = *(const h2*)(drp + 8);

    const float* eb = &etab[et][0];

    float r[ODIM];
#pragma unroll
    for (int o = 0; o < 8; ++o)
        r[o] = (float)sv[o] + (float)dv[o] + eb[o];
    r[8] = (float)sv2[0] + (float)dv2[0] + eb[8];

#pragma unroll
    for (int o = 0; o < ODIM; ++o) r[o] = tanh_fast(r[o]);

    // PLAIN stores: partial lines merge in L2 (write-back) -> no HBM write
    // amplification. (nt stores here caused 3.3x WRITE_SIZE in R6.)
    float* op = out + (size_t)e * ODIM;  // 36B contiguous per thread
    f4 v0 = {r[0], r[1], r[2], r[3]};
    f4 v1 = {r[4], r[5], r[6], r[7]};
    *(f4u*)op = v0;          // dwordx4 (4B-aligned ok)
    *(f4u*)(op + 4) = v1;
    op[8] = r[8];
}

extern "C" void kernel_launch(void* const* d_in, const int* in_sizes, int n_in,
                              void* d_out, int out_size, void* d_ws, size_t ws_size,
                              hipStream_t stream) {
    const float* x      = (const float*)d_in[0];
    const int*   ei     = (const int*)d_in[1];
    const int*   etypes = (const int*)d_in[2];
    const int*   ntypes = (const int*)d_in[3];
    const float* W      = (const float*)d_in[4];
    float* out = (float*)d_out;

    int N = in_sizes[0] / C;    // 100000
    int E = in_sizes[2];        // 1600000

    half_t* sp = (half_t*)d_ws;
    half_t* dp = sp + (size_t)N * PROW;

    int nblocks = (N + 255) / 256;
    node_proj_kernel<<<nblocks, 256, 0, stream>>>(x, ntypes, W, sp, dp, N);

    int eblocks = (E + 255) / 256;
    edge_kernel<<<eblocks, 256, 0, stream>>>(ei, etypes, sp, dp, W, out, E);
}

// Round 8
// 53.551 us; speedup vs baseline: 2.6980x; 1.0629x over previous
//
#include <hip/hip_runtime.h>
#include <math.h>

#define C 64
#define IN_DIM 148
#define ODIM 9      // outputs per edge
// proj row = 9 values, 12-bit fixed point, packed in 16B (one aligned line-piece)
// dequant: v = u/256 - 8   (range +-8, step 1/256, max err 1.95e-3)

typedef _Float16 half_t;
typedef float f4 __attribute__((ext_vector_type(4)));
typedef f4 f4u __attribute__((aligned(4)));
typedef _Float16 h2 __attribute__((ext_vector_type(2)));
typedef unsigned int u32;
typedef u32 u4 __attribute__((ext_vector_type(4)));

__device__ __forceinline__ float tanh_fast(float x) {
    // tanh(x) = 1 - 2/(e^{2x}+1); saturates correctly at +/-inf
    float e = __expf(2.0f * x);
    return 1.0f - 2.0f / (e + 1.0f);
}

__device__ __forceinline__ void decode9(u4 w, int u[ODIM]) {
    // 12-bit fields at bit offsets 12*i in the 128-bit word
    u[0] = w.x & 0xFFF;
    u[1] = (w.x >> 12) & 0xFFF;
    u[2] = __builtin_amdgcn_alignbit(w.y, w.x, 24) & 0xFFF;
    u[3] = (w.y >> 4) & 0xFFF;
    u[4] = (w.y >> 16) & 0xFFF;
    u[5] = __builtin_amdgcn_alignbit(w.z, w.y, 28) & 0xFFF;
    u[6] = (w.z >> 8) & 0xFFF;
    u[7] = (w.z >> 20) & 0xFFF;
    u[8] = w.w & 0xFFF;
}

// ---------------- node projection kernel: 2 threads per node (src/dst half) --
__global__ __launch_bounds__(256) void node_proj_kernel(
    const float* __restrict__ x, const int* __restrict__ node_types,
    const float* __restrict__ W, u4* __restrict__ sp, u4* __restrict__ dp,
    int N)
{
    __shared__ _Float16 Wh[2 * ODIM][C];   // r<9: W[r][c]; r>=9: W[r-9][64+c]  (fp16)
    __shared__ float ntab[2][ODIM][4];     // [0]=src-type consts, [1]=dst-type consts

    for (int i = threadIdx.x; i < 2 * ODIM * C; i += 256) {
        int r = i >> 6, c = i & 63;
        int o = (r < ODIM) ? r : r - ODIM;
        int col = (r < ODIM) ? c : (C + c);
        Wh[r][c] = (_Float16)W[o * IN_DIM + col];
    }
    for (int i = threadIdx.x; i < 2 * ODIM * 4; i += 256) {
        int t = i & 3;
        int o = (i >> 2) % ODIM;
        int sd = (i >> 2) / ODIM;
        ntab[sd][o][t] = W[o * IN_DIM + 128 + sd * 4 + t];
    }
    __syncthreads();

    int tid = blockIdx.x * 256 + threadIdx.x;
    int n = tid >> 1;
    int h = tid & 1;                     // 0 = src half, 1 = dst half
    if (n >= N) return;

    // x row -> fp16 pairs (paired lanes request identical addresses -> merged)
    const f4* xr = (const f4*)(x + (size_t)n * C);
    h2 xh[32];
#pragma unroll
    for (int q = 0; q < 16; ++q) {
        f4 v = xr[q];
        xh[2 * q]     = h2{(_Float16)v.x, (_Float16)v.y};
        xh[2 * q + 1] = h2{(_Float16)v.z, (_Float16)v.w};
    }

    float acc[ODIM];
#pragma unroll
    for (int o = 0; o < ODIM; ++o) acc[o] = 0.0f;

#pragma unroll
    for (int g = 0; g < 8; ++g) {          // 8 halfs (16B) per group
#pragma unroll
        for (int o = 0; o < ODIM; ++o) {
            const h2* wp = (const h2*)&Wh[h * ODIM + o][g * 8];  // ds_read_b128
            acc[o] = __builtin_amdgcn_fdot2(xh[4 * g + 0], wp[0], acc[o], false);
            acc[o] = __builtin_amdgcn_fdot2(xh[4 * g + 1], wp[1], acc[o], false);
            acc[o] = __builtin_amdgcn_fdot2(xh[4 * g + 2], wp[2], acc[o], false);
            acc[o] = __builtin_amdgcn_fdot2(xh[4 * g + 3], wp[3], acc[o], false);
        }
    }

    int t = node_types[n];
    u32 u[ODIM];
#pragma unroll
    for (int o = 0; o < ODIM; ++o) {
        float v = acc[o] + ntab[h][o][t];
        int q = (int)rintf(fmaf(v, 256.0f, 2048.0f));   // (v+8)*256
        q = q < 0 ? 0 : (q > 4095 ? 4095 : q);
        u[o] = (u32)q;
    }
    u4 w;
    w.x = u[0] | (u[1] << 12) | (u[2] << 24);
    w.y = (u[2] >> 8) | (u[3] << 4) | (u[4] << 16) | (u[5] << 28);
    w.z = (u[5] >> 4) | (u[6] << 8) | (u[7] << 20);
    w.w = u[8];

    (h ? dp : sp)[n] = w;                // one 16B aligned store
}

// ---------------- edge kernel: one thread per edge, 2x 16B gathers ----------
__global__ __launch_bounds__(256) void edge_kernel(
    const int* __restrict__ ei, const int* __restrict__ etypes,
    const u4* __restrict__ sp, const u4* __restrict__ dp,
    const float* __restrict__ W, float* __restrict__ out,
    int E)
{
    __shared__ float etab2[12][ODIM];    // etab2[t][o] = W[o][136+t] - 16 (folds 2x dequant offset)
    for (int i = threadIdx.x; i < 12 * ODIM; i += 256) {
        int t = i / ODIM, o = i - t * ODIM;
        etab2[t][o] = W[o * IN_DIM + 136 + t] - 16.0f;
    }
    __syncthreads();

    int e = blockIdx.x * 256 + threadIdx.x;
    if (e >= E) return;

    // streaming index loads: non-temporal so they don't evict the proj set
    int s  = __builtin_nontemporal_load(ei + e);
    int d  = __builtin_nontemporal_load(ei + (size_t)E + e);
    int et = __builtin_nontemporal_load(etypes + e);

    // exactly 2 random lines per edge, 1 instr each, both in flight
    u4 sw = sp[s];
    u4 dw = dp[d];

    int us[ODIM], ud[ODIM];
    decode9(sw, us);
    decode9(dw, ud);

    const float* eb = &etab2[et][0];
    float r[ODIM];
#pragma unroll
    for (int o = 0; o < ODIM; ++o) {
        float v = fmaf((float)(us[o] + ud[o]), 1.0f / 256.0f, eb[o]);
        r[o] = tanh_fast(v);
    }

    // PLAIN stores: partial lines merge in L2 (nt stores caused 3.3x WRITE in R6)
    float* op = out + (size_t)e * ODIM;  // 36B contiguous per thread
    f4 v0 = {r[0], r[1], r[2], r[3]};
    f4 v1 = {r[4], r[5], r[6], r[7]};
    *(f4u*)op = v0;
    *(f4u*)(op + 4) = v1;
    op[8] = r[8];
}

extern "C" void kernel_launch(void* const* d_in, const int* in_sizes, int n_in,
                              void* d_out, int out_size, void* d_ws, size_t ws_size,
                              hipStream_t stream) {
    const float* x      = (const float*)d_in[0];
    const int*   ei     = (const int*)d_in[1];
    const int*   etypes = (const int*)d_in[2];
    const int*   ntypes = (const int*)d_in[3];
    const float* W      = (const float*)d_in[4];
    float* out = (float*)d_out;

    int N = in_sizes[0] / C;    // 100000
    int E = in_sizes[2];        // 1600000

    u4* sp = (u4*)d_ws;                  // N x 16B
    u4* dp = sp + N;                     // N x 16B  (total 3.2 MB)

    int nthreads = N * 2;
    int nblocks  = (nthreads + 255) / 256;
    node_proj_kernel<<<nblocks, 256, 0, stream>>>(x, ntypes, W, sp, dp, N);

    int eblocks = (E + 255) / 256;
    edge_kernel<<<eblocks, 256, 0, stream>>>(ei, etypes, sp, dp, W, out, E);
}